// Round 14
// baseline (224.494 us; speedup 1.0000x reference)
//
#include <hip/hip_runtime.h>
#include <math.h>

#define BN_EPS 1e-5f

typedef __attribute__((ext_vector_type(8))) _Float16 f16x8;
typedef __attribute__((ext_vector_type(4))) _Float16 f16x4;
typedef __attribute__((ext_vector_type(2))) __fp16 fp16v2;
typedef __attribute__((ext_vector_type(4))) float f32x4;

// ---------- helpers ----------

__device__ __forceinline__ float siluf(float v) {
    return v * __builtin_amdgcn_rcpf(1.0f + __expf(-v));
}

// 6*basis_i(x), i=0..3, cubic B-spline on knots g[j]=2j-7.
// 6*B(t) = max(0,2-|t|)^3 - 4*max(0,1-|t|)^3 with t = u-(i+2), u=(x+7)/2.
// The 1/6 is folded into the spline weights at prep time.
__device__ __forceinline__ void expand5(float v, float f[5]) {
    f[0] = siluf(v);
    float u = (v + 7.0f) * 0.5f;
#pragma unroll
    for (int i = 0; i < 4; ++i) {
        float a = fabsf(u - (float)(i + 2));
        float p = fmaxf(2.0f - a, 0.0f);
        float q = fmaxf(1.0f - a, 0.0f);
        f[i + 1] = p * p * p - 4.0f * (q * q * q);
    }
}

__device__ __forceinline__ int pkh(float a, float b) {
    union { fp16v2 h2; int i; } u;
    u.h2 = __builtin_amdgcn_cvt_pkrtz(a, b);
    return u.i;
}

// ---------- merged prep: fc1-w pack + conv2 weights + conv1 weights ----------

__global__ __launch_bounds__(256) void prep_kernel(
        const float* __restrict__ fw1, unsigned int* __restrict__ wTh2,
        const float* __restrict__ bw2, const float* __restrict__ sw2,
        _Float16* __restrict__ Wf,
        const float* __restrict__ bw1, const float* __restrict__ sw1,
        _Float16* __restrict__ Wf1) {
    int blk = blockIdx.x;
    if (blk < 392) {
        int t = blk * 256 + threadIdx.x;
        int o = t & 63;
        int j2 = t >> 6;
        int jc = (j2 * 2) & 63;
        int q2 = (j2 * 2) >> 6;
        wTh2[t] = (unsigned int)pkh(fw1[(size_t)o * 3136 + jc * 49 + q2],
                                    fw1[(size_t)o * 3136 + (jc + 1) * 49 + q2]);
    } else if (blk < 552) {
        int t = (blk - 392) * 256 + threadIdx.x;
        if (t >= 64 * 640) return;
        int n = t / 640;
        int k = t - n * 640;
        int s = k / 160;
        int r = k - s * 160;
        int f = r >> 5;
        int c = r & 31;
        float val = (f == 0) ? bw2[n * 128 + c * 4 + s]
                             : sw2[n * 512 + c * 16 + s * 4 + (f - 1)] * (1.0f / 6.0f);
        Wf[t] = (_Float16)val;
    } else {
        int t = (blk - 552) * 256 + threadIdx.x;
        if (t >= 32 * 64) return;
        int n = t >> 6;
        int k = t & 63;
        int s = k >> 4, j = k & 15;
        float val = 0.f;
        if (j < 15) {
            int f = j / 3, c = j - f * 3;
            int i = c * 4 + s;
            val = (f == 0) ? bw1[n * 12 + i]
                           : sw1[(n * 12 + i) * 4 + f - 1] * (1.0f / 6.0f);
        }
        Wf1[t] = (_Float16)val;
    }
}

// ---------- conv1: per-IMAGE block, unique-pixel expand + MFMA + pool + stats ----

__global__ __launch_bounds__(256, 4) void conv1_kernel(
        const float* __restrict__ x, const _Float16* __restrict__ Wf1,
        _Float16* __restrict__ pooled, float* __restrict__ part) {
    __shared__ _Float16 Eu[1025 * 16];
    __shared__ float Rs[4][64];
    char* EuB = (char*)Eu;

    int t = threadIdx.x;
    int lane = t & 63, wv = t >> 6;
    int quad = lane >> 4, l15 = lane & 15;
    int b = blockIdx.x;

    const _Float16* wb0 = Wf1 + (size_t)l15 * 64 + quad * 8;
    f16x8 bf00 = *(const f16x8*)(wb0);
    f16x8 bf01 = *(const f16x8*)(wb0 + 32);
    f16x8 bf10 = *(const f16x8*)(wb0 + 16 * 64);
    f16x8 bf11 = *(const f16x8*)(wb0 + 16 * 64 + 32);

    float xv[12];
    const float* xb = x + (size_t)b * 3072;
#pragma unroll
    for (int k = 0; k < 12; ++k) xv[k] = xb[t + k * 256];
#pragma unroll
    for (int k = 0; k < 12; ++k) {
        int idx = t + k * 256;
        int c = idx >> 10;
        int pos = idx & 1023;
        float f[5];
        expand5(xv[k], f);
        int rb = pos * 32;
        int key = (pos & 12) << 2;
        *(_Float16*)(EuB + ((rb + c * 2) ^ key))        = (_Float16)f[0];
        *(_Float16*)(EuB + ((rb + (3 + c) * 2) ^ key))  = (_Float16)f[1];
        *(_Float16*)(EuB + ((rb + (6 + c) * 2) ^ key))  = (_Float16)f[2];
        *(_Float16*)(EuB + ((rb + (9 + c) * 2) ^ key))  = (_Float16)f[3];
        *(_Float16*)(EuB + ((rb + (12 + c) * 2) ^ key)) = (_Float16)f[4];
    }
    if (t < 8) *(int*)(EuB + 32768 + t * 4) = 0;
    __syncthreads();

    int dxq = quad >> 1, hb = (quad & 1) * 16;
    int wxv = 8 * wv + (l15 & 7);
    int colb = wxv + dxq;
    int pbase = (colb * 32 + hb) ^ ((colb & 12) << 2);
    bool vx = wxv < 31;
    int pzero = 32768 + hb;
    int wy0 = l15 >> 3;

    float ss0 = 0.f, sq0 = 0.f, ss1 = 0.f, sq1 = 0.f;

    int p0 = vx ? wy0 * 1024 + pbase : pzero;
    f16x8 a0 = *(const f16x8*)(EuB + p0);
    f16x8 a1 = *(const f16x8*)(EuB + p0 + (vx ? 1024 : 0));

#pragma unroll 1
    for (int i = 0; i < 16; ++i) {
        f32x4 acc0 = (f32x4){0.f, 0.f, 0.f, 0.f};
        f32x4 acc1 = (f32x4){0.f, 0.f, 0.f, 0.f};
        acc0 = __builtin_amdgcn_mfma_f32_16x16x32_f16(a0, bf00, acc0, 0, 0, 0);
        acc1 = __builtin_amdgcn_mfma_f32_16x16x32_f16(a0, bf10, acc1, 0, 0, 0);
        acc0 = __builtin_amdgcn_mfma_f32_16x16x32_f16(a1, bf01, acc0, 0, 0, 0);
        acc1 = __builtin_amdgcn_mfma_f32_16x16x32_f16(a1, bf11, acc1, 0, 0, 0);
        if (i < 15) {
            int wyn = 2 * (i + 1) + wy0;
            bool vn = vx && (wyn < 31);
            int pn = vn ? wyn * 1024 + pbase : pzero;
            a0 = *(const f16x8*)(EuB + pn);
            a1 = *(const f16x8*)(EuB + pn + (vn ? 1024 : 0));
        }
        float h00 = fmaxf(acc0[0], acc0[1]);
        float h01 = fmaxf(acc0[2], acc0[3]);
        float h10 = fmaxf(acc1[0], acc1[1]);
        float h11 = fmaxf(acc1[2], acc1[3]);
        float g00 = fmaxf(h00, __shfl_down(h00, 32, 64));
        float g01 = fmaxf(h01, __shfl_down(h01, 32, 64));
        float g10 = fmaxf(h10, __shfl_down(h10, 32, 64));
        float g11 = fmaxf(h11, __shfl_down(h11, 32, 64));
        if (lane < 32 && i < 15) {
            int pn0 = 4 * wv + (quad & 1) * 2;
            size_t base = ((size_t)b * 225 + i * 15) * 32;
            if (pn0 < 15) {
                pooled[base + pn0 * 32 + l15]      = (_Float16)g00;
                pooled[base + pn0 * 32 + 16 + l15] = (_Float16)g10;
            }
            if (pn0 < 14) {
                pooled[base + (pn0 + 1) * 32 + l15]      = (_Float16)g01;
                pooled[base + (pn0 + 1) * 32 + 16 + l15] = (_Float16)g11;
            }
        }
        ss0 += acc0[0] + acc0[1] + acc0[2] + acc0[3];
        sq0 += acc0[0] * acc0[0] + acc0[1] * acc0[1]
             + acc0[2] * acc0[2] + acc0[3] * acc0[3];
        ss1 += acc1[0] + acc1[1] + acc1[2] + acc1[3];
        sq1 += acc1[0] * acc1[0] + acc1[1] * acc1[1]
             + acc1[2] * acc1[2] + acc1[3] * acc1[3];
    }

    ss0 += __shfl_down(ss0, 32, 64); ss0 += __shfl_down(ss0, 16, 64);
    sq0 += __shfl_down(sq0, 32, 64); sq0 += __shfl_down(sq0, 16, 64);
    ss1 += __shfl_down(ss1, 32, 64); ss1 += __shfl_down(ss1, 16, 64);
    sq1 += __shfl_down(sq1, 32, 64); sq1 += __shfl_down(sq1, 16, 64);
    if (lane < 16) {
        Rs[wv][2 * l15]          = ss0;
        Rs[wv][2 * l15 + 1]      = sq0;
        Rs[wv][32 + 2 * l15]     = ss1;
        Rs[wv][32 + 2 * l15 + 1] = sq1;
    }
    __syncthreads();
    if (t < 64)
        part[(size_t)b * 64 + t] = Rs[0][t] + Rs[1][t] + Rs[2][t] + Rs[3][t];
}

// ---------- conv2: 2x2 wave tiling + B double-buffer (the clean experiment) ----------
// LDS accounting (r13 post-mortem): N-split reads every A-row 4x -> 5MB/CU
// (~60K cyc) + 30K conflict cyc = 71% of conv2's budget. 2x2 tiling halves
// A-reads (each feeds 2 MFMAs). r8 proved the concept but dropped the
// B-pipeline; here B keeps the r7-proven one-group-ahead double buffer
// (10 frags/buffer) and 4 independent acc chains (r12 lesson).

#define EU_PS 160  // halves per position, unpadded

__device__ __forceinline__ void c2_loadb2(const _Float16* __restrict__ Wb0,
                                          const _Float16* __restrict__ Wb1,
                                          int g, f16x8 bf[2][5]) {
#pragma unroll
    for (int ks = 0; ks < 5; ++ks) {
        bf[0][ks] = *(const f16x8*)(Wb0 + g * 160 + ks * 32);
        bf[1][ks] = *(const f16x8*)(Wb1 + g * 160 + ks * 32);
    }
}

__device__ __forceinline__ void c2_mfma2(const _Float16* Eu,
                                         const int abase[2][4], int g,
                                         int quad, const f16x8 bf[2][5],
                                         f32x4 acc[2][2]) {
#pragma unroll
    for (int ks = 0; ks < 5; ++ks) {
        int jo = ks * 32 + quad * 8;
        f16x8 aA = *(const f16x8*)&Eu[abase[0][g] + jo];
        acc[0][0] = __builtin_amdgcn_mfma_f32_16x16x32_f16(aA, bf[0][ks], acc[0][0], 0, 0, 0);
        acc[0][1] = __builtin_amdgcn_mfma_f32_16x16x32_f16(aA, bf[1][ks], acc[0][1], 0, 0, 0);
        f16x8 aB = *(const f16x8*)&Eu[abase[1][g] + jo];
        acc[1][0] = __builtin_amdgcn_mfma_f32_16x16x32_f16(aB, bf[0][ks], acc[1][0], 0, 0, 0);
        acc[1][1] = __builtin_amdgcn_mfma_f32_16x16x32_f16(aB, bf[1][ks], acc[1][1], 0, 0, 0);
    }
}

__global__ __launch_bounds__(256, 4) void conv2_kernel(
        const _Float16* __restrict__ pooled, const float* __restrict__ stats1,
        const float* __restrict__ g1v, const float* __restrict__ b1v,
        const _Float16* __restrict__ Wf, _Float16* __restrict__ Pt,
        float* __restrict__ part) {
    __shared__ _Float16 Eu[65 * EU_PS];
    __shared__ float Rs[4][64];

    int t = threadIdx.x;
    int lane = t & 63, wv = t >> 6;
    int quad = lane >> 4, l15 = lane & 15;
    int mw = wv >> 1, nw = wv & 1;

    int blk = blockIdx.x;
    int b = blk >> 2;
    int py0 = ((blk >> 1) & 1) * 7;
    int px0 = (blk & 1) * 7;

    const _Float16* Wb0 = Wf + (size_t)(nw * 32 + l15) * 640 + quad * 8;
    const _Float16* Wb1 = Wb0 + 16 * 640;
    f16x8 bfA[2][5], bfB[2][5];
    c2_loadb2(Wb0, Wb1, 0, bfA);

    // ---- phase 1: 8x8 pixels x 32 ch; thread = (c-pair, xx, y-half) ----
    {
        int c2 = t & 15, c0 = c2 * 2;
        int xx = (t >> 4) & 7;
        int yh = t >> 7;
        const float invN1 = 1.0f / (1024.0f * 961.0f);
        float m0 = stats1[2 * c0] * invN1;
        float v0 = stats1[2 * c0 + 1] * invN1 - m0 * m0;
        float sc0 = rsqrtf(v0 + BN_EPS) * g1v[c0];
        float sh0 = b1v[c0] - m0 * sc0;
        float m1 = stats1[2 * c0 + 2] * invN1;
        float v1 = stats1[2 * c0 + 3] * invN1 - m1 * m1;
        float sc1 = rsqrtf(v1 + BN_EPS) * g1v[c0 + 1];
        float sh1 = b1v[c0 + 1] - m1 * sc1;
        const _Float16* pbase0 =
            pooled + ((size_t)b * 225 + py0 * 15 + px0) * 32 + c0;
#pragma unroll
        for (int yi = 0; yi < 4; ++yi) {
            int yr = yh * 4 + yi;
            fp16v2 v2 = *(const fp16v2*)(pbase0 + yr * 480 + xx * 32);
            float va = fmaxf((float)v2.x * sc0 + sh0, 0.f);
            float vb = fmaxf((float)v2.y * sc1 + sh1, 0.f);
            float fa[5], fb5[5];
            expand5(va, fa);
            expand5(vb, fb5);
            int* eb = (int*)&Eu[(yr * 8 + xx) * EU_PS] + c2;
            eb[0]  = pkh(fa[0], fb5[0]);
            eb[16] = pkh(fa[1], fb5[1]);
            eb[32] = pkh(fa[2], fb5[2]);
            eb[48] = pkh(fa[3], fb5[3]);
            eb[64] = pkh(fa[4], fb5[4]);
        }
    }
    if (t < 80) ((int*)&Eu[64 * EU_PS])[t] = 0;  // zero position

    // per-lane A row bases for this wave's two 16-row tiles
    int abase[2][4];
#pragma unroll
    for (int mt = 0; mt < 2; ++mt) {
        int m = mw * 32 + mt * 16 + l15;
        if (m < 49) {
            int pr = m / 7, pc = m - pr * 7;
#pragma unroll
            for (int s = 0; s < 4; ++s)
                abase[mt][s] = ((pr + (s >> 1)) * 8 + pc + (s & 1)) * EU_PS;
        } else {
#pragma unroll
            for (int s = 0; s < 4; ++s) abase[mt][s] = 64 * EU_PS;
        }
    }
    __syncthreads();

    f32x4 acc[2][2];
#pragma unroll
    for (int mt = 0; mt < 2; ++mt)
#pragma unroll
        for (int nt = 0; nt < 2; ++nt)
            acc[mt][nt] = (f32x4){0.f, 0.f, 0.f, 0.f};

    c2_loadb2(Wb0, Wb1, 1, bfB);
    c2_mfma2(Eu, abase, 0, quad, bfA, acc);
    c2_loadb2(Wb0, Wb1, 2, bfA);
    c2_mfma2(Eu, abase, 1, quad, bfB, acc);
    c2_loadb2(Wb0, Wb1, 3, bfB);
    c2_mfma2(Eu, abase, 2, quad, bfA, acc);
    c2_mfma2(Eu, abase, 3, quad, bfB, acc);

    // ---- store fp16 Pt: rows mw*32 + mt*16 + quad*4 + reg, cols nw*32 + nt*16 + l15 ----
#pragma unroll
    for (int mt = 0; mt < 2; ++mt) {
#pragma unroll
        for (int reg = 0; reg < 4; ++reg) {
            int m = mw * 32 + mt * 16 + quad * 4 + reg;
            if (m < 49) {
                int pr = m / 7, pc = m - pr * 7;
                int patch = (b * 14 + py0 + pr) * 14 + px0 + pc;
#pragma unroll
                for (int nt = 0; nt < 2; ++nt)
                    Pt[(size_t)patch * 64 + nw * 32 + nt * 16 + l15] =
                        (_Float16)acc[mt][nt][reg];
            }
        }
    }
    // ---- stats: per-nt col sums over this wave's 32 rows ----
#pragma unroll
    for (int nt = 0; nt < 2; ++nt) {
        float s = 0.f, s2 = 0.f;
#pragma unroll
        for (int mt = 0; mt < 2; ++mt)
#pragma unroll
            for (int reg = 0; reg < 4; ++reg) {
                float a = acc[mt][nt][reg];
                s += a;
                s2 += a * a;
            }
        s  += __shfl_down(s, 16, 64);  s  += __shfl_down(s, 32, 64);
        s2 += __shfl_down(s2, 16, 64); s2 += __shfl_down(s2, 32, 64);
        if (lane < 16) {
            Rs[wv][nt * 32 + 2 * l15]     = s;
            Rs[wv][nt * 32 + 2 * l15 + 1] = s2;
        }
    }
    __syncthreads();
    // combine the two mw-waves per nw; part layout [blk][128] unchanged
    if (t < 128) {
        int o = t >> 1;               // global col
        int nwv = o >> 5;             // which nw owns this col
        int lidx = (o & 31) * 2 + (t & 1);
        part[(size_t)blk * 128 + t] = Rs[nwv][lidx] + Rs[nwv + 2][lidx];
    }
}

// ---------- reduce slot-major partials ----------

__global__ __launch_bounds__(256) void redstats_kernel(
        const float* __restrict__ part, float* __restrict__ stats,
        int nblk, int stride) {
    int p = blockIdx.x;
    float s = 0.f;
    for (int j = threadIdx.x; j < nblk; j += 256)
        s += part[(size_t)j * stride + p];
#pragma unroll
    for (int off = 32; off > 0; off >>= 1) s += __shfl_down(s, off, 64);
    __shared__ float ls[4];
    if ((threadIdx.x & 63) == 0) ls[threadIdx.x >> 6] = s;
    __syncthreads();
    if (threadIdx.x == 0) stats[p] = ls[0] + ls[1] + ls[2] + ls[3];
}

// ---------- BN + ReLU + pool, fp16 in/out, 4 ch per thread ----------

__global__ __launch_bounds__(256) void bnpool2_kernel(
        const _Float16* __restrict__ Pt, const float* __restrict__ stats,
        const float* __restrict__ g, const float* __restrict__ bb,
        _Float16* __restrict__ out) {
    int t = blockIdx.x * 256 + threadIdx.x;
    if (t >= 1024 * 49 * 16) return;
    int c4 = (t & 15) * 4;
    int q2 = (t >> 4) % 49;
    int b  = t / (49 * 16);
    float sc[4], sh[4];
#pragma unroll
    for (int j = 0; j < 4; ++j) {
        int c = c4 + j;
        float mean = stats[2 * c] * (1.0f / 200704.0f);
        float var  = stats[2 * c + 1] * (1.0f / 200704.0f) - mean * mean;
        sc[j] = rsqrtf(var + BN_EPS) * g[c];
        sh[j] = bb[c] - mean * sc[j];
    }
    int py2 = q2 / 7, px2 = q2 - py2 * 7;
    int q = (py2 * 2) * 14 + px2 * 2;
    const _Float16* p = Pt + ((size_t)b * 196 + q) * 64 + c4;
    f16x4 r0 = *(const f16x4*)(p);
    f16x4 r1 = *(const f16x4*)(p + 64);
    f16x4 r2 = *(const f16x4*)(p + 14 * 64);
    f16x4 r3 = *(const f16x4*)(p + 15 * 64);
    f16x4 res;
#pragma unroll
    for (int j = 0; j < 4; ++j) {
        float v0 = fmaxf((float)r0[j] * sc[j] + sh[j], 0.f);
        float v1 = fmaxf((float)r1[j] * sc[j] + sh[j], 0.f);
        float v2 = fmaxf((float)r2[j] * sc[j] + sh[j], 0.f);
        float v3 = fmaxf((float)r3[j] * sc[j] + sh[j], 0.f);
        res[j] = (_Float16)fmaxf(fmaxf(v0, v1), fmaxf(v2, v3));
    }
    *(f16x4*)(out + (size_t)b * 3136 + q2 * 64 + c4) = res;
}

// ---------- fc1: 2 images/block, fdot2 ----------

__global__ __launch_bounds__(256) void fc1_kernel(
        const _Float16* __restrict__ xin, const unsigned int* __restrict__ wTh2,
        const float* __restrict__ bias, float* __restrict__ z) {
    __shared__ unsigned int xsu[2 * 1568];
    __shared__ float red[2][4][64];
    int b0 = blockIdx.x * 2;
    const unsigned int* xg = (const unsigned int*)xin + (size_t)b0 * 1568;
    for (int j = threadIdx.x; j < 2 * 1568; j += 256) xsu[j] = xg[j];
    __syncthreads();
    int o = threadIdx.x & 63, q = threadIdx.x >> 6;
    float s0 = 0.f, s1 = 0.f;
    const unsigned int* wp = wTh2 + (size_t)q * 392 * 64 + o;
    int jb = q * 392;
    for (int i = 0; i < 392; ++i) {
        union { unsigned int u; fp16v2 h; } uw, u0, u1;
        uw.u = wp[i * 64];
        u0.u = xsu[jb + i];
        u1.u = xsu[1568 + jb + i];
        s0 = __builtin_amdgcn_fdot2(u0.h, uw.h, s0, false);
        s1 = __builtin_amdgcn_fdot2(u1.h, uw.h, s1, false);
    }
    red[0][q][o] = s0; red[1][q][o] = s1;
    __syncthreads();
    if (threadIdx.x < 128) {
        int bb = threadIdx.x >> 6;
        int oo = threadIdx.x & 63;
        float tot = red[bb][0][oo] + red[bb][1][oo] + red[bb][2][oo]
                  + red[bb][3][oo] + bias[oo];
        z[((size_t)(b0 + bb)) * 64 + oo] = tot;
    }
}

// ---------- bn1d column stats -> precomputed sc/sh ----------

__global__ __launch_bounds__(256) void colstats_kernel(
        const float* __restrict__ z, const float* __restrict__ g,
        const float* __restrict__ bb, float* __restrict__ scsh) {
    int c = blockIdx.x;
    float s = 0.f, s2 = 0.f;
    for (int b = threadIdx.x; b < 1024; b += 256) {
        float v = z[(size_t)b * 64 + c];
        s += v; s2 += v * v;
    }
#pragma unroll
    for (int off = 32; off > 0; off >>= 1) {
        s  += __shfl_down(s, off, 64);
        s2 += __shfl_down(s2, off, 64);
    }
    __shared__ float ls[8];
    int w = threadIdx.x >> 6;
    if ((threadIdx.x & 63) == 0) { ls[w * 2] = s; ls[w * 2 + 1] = s2; }
    __syncthreads();
    if (threadIdx.x == 0) {
        float st = ls[0] + ls[2] + ls[4] + ls[6];
        float st2 = ls[1] + ls[3] + ls[5] + ls[7];
        float mean = st * (1.0f / 1024.0f);
        float var  = st2 * (1.0f / 1024.0f) - mean * mean;
        float sc = rsqrtf(var + BN_EPS) * g[c];
        scsh[2 * c]     = sc;
        scsh[2 * c + 1] = bb[c] - mean * sc;
    }
}

// ---------- final: bn1d + relu + fc2 -> out [1024,10] ----------

__global__ __launch_bounds__(256) void final_kernel(
        const float* __restrict__ z, const float* __restrict__ scsh,
        const float* __restrict__ w2, const float* __restrict__ b2,
        float* __restrict__ out) {
    int t = blockIdx.x * 256 + threadIdx.x;
    if (t >= 10240) return;
    int o = t % 10, b = t / 10;
    float acc = b2[o];
#pragma unroll 8
    for (int c = 0; c < 64; ++c) {
        float a = fmaxf(z[(size_t)b * 64 + c] * scsh[2 * c] + scsh[2 * c + 1], 0.f);
        acc += a * w2[o * 64 + c];
    }
    out[t] = acc;
}

// ---------- launch ----------

extern "C" void kernel_launch(void* const* d_in, const int* in_sizes, int n_in,
                              void* d_out, int out_size, void* d_ws, size_t ws_size,
                              hipStream_t stream) {
    const float* x   = (const float*)d_in[0];
    const float* bw1 = (const float*)d_in[1];
    const float* sw1 = (const float*)d_in[2];
    const float* g1  = (const float*)d_in[3];
    const float* b1  = (const float*)d_in[4];
    const float* bw2 = (const float*)d_in[5];
    const float* sw2 = (const float*)d_in[6];
    const float* g2  = (const float*)d_in[7];
    const float* b2v = (const float*)d_in[8];
    const float* fw1 = (const float*)d_in[9];
    const float* fb1 = (const float*)d_in[10];
    const float* g3  = (const float*)d_in[11];
    const float* b3  = (const float*)d_in[12];
    const float* fw2 = (const float*)d_in[13];
    const float* fb2 = (const float*)d_in[14];
    float* out = (float*)d_out;

    char* ws = (char*)d_ws;
    float* part1     = (float*)(ws);
    _Float16* Pt     = (_Float16*)(ws);
    float* part2     = (float*)(ws + 51380224);
    _Float16* Wf     = (_Float16*)(ws + 100000000);
    _Float16* Wf1    = (_Float16*)(ws + 100131072);
    _Float16* pooled = (_Float16*)(ws + 125960192);
    float* z         = (float*)(ws + 155451392);
    unsigned int* wTh2 = (unsigned int*)(ws + 155713536);
    float* stats1    = (float*)(ws + 156516352);
    float* stats2    = (float*)(ws + 156516608);
    float* stats3    = (float*)(ws + 156517120);

    prep_kernel<<<560, 256, 0, stream>>>(fw1, wTh2, bw2, sw2, Wf, bw1, sw1, Wf1);

    conv1_kernel<<<1024, 256, 0, stream>>>(x, Wf1, pooled, part1);
    redstats_kernel<<<64, 256, 0, stream>>>(part1, stats1, 1024, 64);

    conv2_kernel<<<4096, 256, 0, stream>>>(pooled, stats1, g1, b1,
                                           Wf, Pt, part2);
    redstats_kernel<<<128, 256, 0, stream>>>(part2, stats2, 4096, 128);

    _Float16* pooled2 = pooled;
    bnpool2_kernel<<<(1024 * 49 * 16 + 255) / 256, 256, 0, stream>>>(
        Pt, stats2, g2, b2v, pooled2);

    fc1_kernel<<<512, 256, 0, stream>>>(pooled2, wTh2, fb1, z);
    colstats_kernel<<<64, 256, 0, stream>>>(z, g3, b3, stats3);
    final_kernel<<<(10240 + 255) / 256, 256, 0, stream>>>(z, stats3, fw2, fb2, out);
}

// Round 15
// 201.843 us; speedup vs baseline: 1.1122x; 1.1122x over previous
//
#include <hip/hip_runtime.h>
#include <math.h>

#define BN_EPS 1e-5f

typedef __attribute__((ext_vector_type(8))) _Float16 f16x8;
typedef __attribute__((ext_vector_type(4))) _Float16 f16x4;
typedef __attribute__((ext_vector_type(2))) __fp16 fp16v2;
typedef __attribute__((ext_vector_type(4))) float f32x4;

// ---------- helpers ----------

__device__ __forceinline__ float siluf(float v) {
    return v * __builtin_amdgcn_rcpf(1.0f + __expf(-v));
}

// 6*basis_i(x), i=0..3, cubic B-spline on knots g[j]=2j-7.
// 6*B(t) = max(0,2-|t|)^3 - 4*max(0,1-|t|)^3 with t = u-(i+2), u=(x+7)/2.
// The 1/6 is folded into the spline weights at prep time.
__device__ __forceinline__ void expand5(float v, float f[5]) {
    f[0] = siluf(v);
    float u = (v + 7.0f) * 0.5f;
#pragma unroll
    for (int i = 0; i < 4; ++i) {
        float a = fabsf(u - (float)(i + 2));
        float p = fmaxf(2.0f - a, 0.0f);
        float q = fmaxf(1.0f - a, 0.0f);
        f[i + 1] = p * p * p - 4.0f * (q * q * q);
    }
}

__device__ __forceinline__ int pkh(float a, float b) {
    union { fp16v2 h2; int i; } u;
    u.h2 = __builtin_amdgcn_cvt_pkrtz(a, b);
    return u.i;
}

// ---------- merged prep: fc1-w pack + conv2 weights + conv1 weights + stats1 zero ----------

__global__ __launch_bounds__(256) void prep_kernel(
        const float* __restrict__ fw1, unsigned int* __restrict__ wTh2,
        const float* __restrict__ bw2, const float* __restrict__ sw2,
        _Float16* __restrict__ Wf,
        const float* __restrict__ bw1, const float* __restrict__ sw1,
        _Float16* __restrict__ Wf1, float* __restrict__ stats1) {
    int blk = blockIdx.x;
    if (blk < 392) {
        int t = blk * 256 + threadIdx.x;
        int o = t & 63;
        int j2 = t >> 6;
        int jc = (j2 * 2) & 63;
        int q2 = (j2 * 2) >> 6;
        wTh2[t] = (unsigned int)pkh(fw1[(size_t)o * 3136 + jc * 49 + q2],
                                    fw1[(size_t)o * 3136 + (jc + 1) * 49 + q2]);
    } else if (blk < 552) {
        int t = (blk - 392) * 256 + threadIdx.x;
        if (t >= 64 * 640) return;
        int n = t / 640;
        int k = t - n * 640;
        int s = k / 160;
        int r = k - s * 160;
        int f = r >> 5;
        int c = r & 31;
        float val = (f == 0) ? bw2[n * 128 + c * 4 + s]
                             : sw2[n * 512 + c * 16 + s * 4 + (f - 1)] * (1.0f / 6.0f);
        Wf[t] = (_Float16)val;
    } else {
        int tid = threadIdx.x;
        if (blk == 559 && tid < 64) stats1[tid] = 0.f;  // re-zeroed every launch
        int t = (blk - 552) * 256 + tid;
        if (t >= 32 * 64) return;
        int n = t >> 6;
        int k = t & 63;
        int s = k >> 4, j = k & 15;
        float val = 0.f;
        if (j < 15) {
            int f = j / 3, c = j - f * 3;
            int i = c * 4 + s;
            val = (f == 0) ? bw1[n * 12 + i]
                           : sw1[(n * 12 + i) * 4 + f - 1] * (1.0f / 6.0f);
        }
        Wf1[t] = (_Float16)val;
    }
}

// ---------- conv1: per-IMAGE block; stats accumulate via atomicAdd (no redstats1) ----

__global__ __launch_bounds__(256, 4) void conv1_kernel(
        const float* __restrict__ x, const _Float16* __restrict__ Wf1,
        _Float16* __restrict__ pooled, float* __restrict__ stats1) {
    __shared__ _Float16 Eu[1025 * 16];
    __shared__ float Rs[4][64];
    char* EuB = (char*)Eu;

    int t = threadIdx.x;
    int lane = t & 63, wv = t >> 6;
    int quad = lane >> 4, l15 = lane & 15;
    int b = blockIdx.x;

    const _Float16* wb0 = Wf1 + (size_t)l15 * 64 + quad * 8;
    f16x8 bf00 = *(const f16x8*)(wb0);
    f16x8 bf01 = *(const f16x8*)(wb0 + 32);
    f16x8 bf10 = *(const f16x8*)(wb0 + 16 * 64);
    f16x8 bf11 = *(const f16x8*)(wb0 + 16 * 64 + 32);

    float xv[12];
    const float* xb = x + (size_t)b * 3072;
#pragma unroll
    for (int k = 0; k < 12; ++k) xv[k] = xb[t + k * 256];
#pragma unroll
    for (int k = 0; k < 12; ++k) {
        int idx = t + k * 256;
        int c = idx >> 10;
        int pos = idx & 1023;
        float f[5];
        expand5(xv[k], f);
        int rb = pos * 32;
        int key = (pos & 12) << 2;
        *(_Float16*)(EuB + ((rb + c * 2) ^ key))        = (_Float16)f[0];
        *(_Float16*)(EuB + ((rb + (3 + c) * 2) ^ key))  = (_Float16)f[1];
        *(_Float16*)(EuB + ((rb + (6 + c) * 2) ^ key))  = (_Float16)f[2];
        *(_Float16*)(EuB + ((rb + (9 + c) * 2) ^ key))  = (_Float16)f[3];
        *(_Float16*)(EuB + ((rb + (12 + c) * 2) ^ key)) = (_Float16)f[4];
    }
    if (t < 8) *(int*)(EuB + 32768 + t * 4) = 0;
    __syncthreads();

    int dxq = quad >> 1, hb = (quad & 1) * 16;
    int wxv = 8 * wv + (l15 & 7);
    int colb = wxv + dxq;
    int pbase = (colb * 32 + hb) ^ ((colb & 12) << 2);
    bool vx = wxv < 31;
    int pzero = 32768 + hb;
    int wy0 = l15 >> 3;

    float ss0 = 0.f, sq0 = 0.f, ss1 = 0.f, sq1 = 0.f;

    int p0 = vx ? wy0 * 1024 + pbase : pzero;
    f16x8 a0 = *(const f16x8*)(EuB + p0);
    f16x8 a1 = *(const f16x8*)(EuB + p0 + (vx ? 1024 : 0));

#pragma unroll 1
    for (int i = 0; i < 16; ++i) {
        f32x4 acc0 = (f32x4){0.f, 0.f, 0.f, 0.f};
        f32x4 acc1 = (f32x4){0.f, 0.f, 0.f, 0.f};
        acc0 = __builtin_amdgcn_mfma_f32_16x16x32_f16(a0, bf00, acc0, 0, 0, 0);
        acc1 = __builtin_amdgcn_mfma_f32_16x16x32_f16(a0, bf10, acc1, 0, 0, 0);
        acc0 = __builtin_amdgcn_mfma_f32_16x16x32_f16(a1, bf01, acc0, 0, 0, 0);
        acc1 = __builtin_amdgcn_mfma_f32_16x16x32_f16(a1, bf11, acc1, 0, 0, 0);
        if (i < 15) {
            int wyn = 2 * (i + 1) + wy0;
            bool vn = vx && (wyn < 31);
            int pn = vn ? wyn * 1024 + pbase : pzero;
            a0 = *(const f16x8*)(EuB + pn);
            a1 = *(const f16x8*)(EuB + pn + (vn ? 1024 : 0));
        }
        float h00 = fmaxf(acc0[0], acc0[1]);
        float h01 = fmaxf(acc0[2], acc0[3]);
        float h10 = fmaxf(acc1[0], acc1[1]);
        float h11 = fmaxf(acc1[2], acc1[3]);
        float g00 = fmaxf(h00, __shfl_down(h00, 32, 64));
        float g01 = fmaxf(h01, __shfl_down(h01, 32, 64));
        float g10 = fmaxf(h10, __shfl_down(h10, 32, 64));
        float g11 = fmaxf(h11, __shfl_down(h11, 32, 64));
        if (lane < 32 && i < 15) {
            int pn0 = 4 * wv + (quad & 1) * 2;
            size_t base = ((size_t)b * 225 + i * 15) * 32;
            if (pn0 < 15) {
                pooled[base + pn0 * 32 + l15]      = (_Float16)g00;
                pooled[base + pn0 * 32 + 16 + l15] = (_Float16)g10;
            }
            if (pn0 < 14) {
                pooled[base + (pn0 + 1) * 32 + l15]      = (_Float16)g01;
                pooled[base + (pn0 + 1) * 32 + 16 + l15] = (_Float16)g11;
            }
        }
        ss0 += acc0[0] + acc0[1] + acc0[2] + acc0[3];
        sq0 += acc0[0] * acc0[0] + acc0[1] * acc0[1]
             + acc0[2] * acc0[2] + acc0[3] * acc0[3];
        ss1 += acc1[0] + acc1[1] + acc1[2] + acc1[3];
        sq1 += acc1[0] * acc1[0] + acc1[1] * acc1[1]
             + acc1[2] * acc1[2] + acc1[3] * acc1[3];
    }

    ss0 += __shfl_down(ss0, 32, 64); ss0 += __shfl_down(ss0, 16, 64);
    sq0 += __shfl_down(sq0, 32, 64); sq0 += __shfl_down(sq0, 16, 64);
    ss1 += __shfl_down(ss1, 32, 64); ss1 += __shfl_down(ss1, 16, 64);
    sq1 += __shfl_down(sq1, 32, 64); sq1 += __shfl_down(sq1, 16, 64);
    if (lane < 16) {
        Rs[wv][2 * l15]          = ss0;
        Rs[wv][2 * l15 + 1]      = sq0;
        Rs[wv][32 + 2 * l15]     = ss1;
        Rs[wv][32 + 2 * l15 + 1] = sq1;
    }
    __syncthreads();
    if (t < 64)
        atomicAdd(&stats1[t], Rs[0][t] + Rs[1][t] + Rs[2][t] + Rs[3][t]);
}

// ---------- conv2: r13-exact N-split (measured 52.7 us) ----------

#define EU_PS 160  // halves per position, unpadded

__device__ __forceinline__ void c2_loadb(const _Float16* __restrict__ Wb,
                                         int g, f16x8 bf[5]) {
#pragma unroll
    for (int ks = 0; ks < 5; ++ks)
        bf[ks] = *(const f16x8*)(Wb + g * 160 + ks * 32);
}

__device__ __forceinline__ void c2_mfma(const _Float16* Eu,
                                        const int abase[4][4], int g,
                                        int quad, const f16x8 bf[5],
                                        f32x4 acc[4]) {
#pragma unroll
    for (int ks = 0; ks < 5; ++ks) {
        int jo = ks * 32 + quad * 8;
#pragma unroll
        for (int mt = 0; mt < 4; ++mt) {
            f16x8 a = *(const f16x8*)&Eu[abase[mt][g] + jo];
            acc[mt] = __builtin_amdgcn_mfma_f32_16x16x32_f16(a, bf[ks], acc[mt], 0, 0, 0);
        }
    }
}

__global__ __launch_bounds__(256, 7) void conv2_kernel(
        const _Float16* __restrict__ pooled, const float* __restrict__ stats1,
        const float* __restrict__ g1v, const float* __restrict__ b1v,
        const _Float16* __restrict__ Wf, _Float16* __restrict__ Pt,
        float* __restrict__ part) {
    __shared__ _Float16 Eu[65 * EU_PS];

    int t = threadIdx.x;
    int lane = t & 63, wv = t >> 6;
    int quad = lane >> 4, l15 = lane & 15;

    int blk = blockIdx.x;
    int b = blk >> 2;
    int py0 = ((blk >> 1) & 1) * 7;
    int px0 = (blk & 1) * 7;

    const _Float16* Wb = Wf + (size_t)(wv * 16 + l15) * 640 + quad * 8;
    f16x8 bfA[5], bfB[5];
    c2_loadb(Wb, 0, bfA);

    // ---- phase 1: 8x8 pixels x 32 ch; thread = (c-pair, xx, y-half) ----
    {
        int c2 = t & 15, c0 = c2 * 2;
        int xx = (t >> 4) & 7;
        int yh = t >> 7;
        const float invN1 = 1.0f / (1024.0f * 961.0f);
        float m0 = stats1[2 * c0] * invN1;
        float v0 = stats1[2 * c0 + 1] * invN1 - m0 * m0;
        float sc0 = rsqrtf(v0 + BN_EPS) * g1v[c0];
        float sh0 = b1v[c0] - m0 * sc0;
        float m1 = stats1[2 * c0 + 2] * invN1;
        float v1 = stats1[2 * c0 + 3] * invN1 - m1 * m1;
        float sc1 = rsqrtf(v1 + BN_EPS) * g1v[c0 + 1];
        float sh1 = b1v[c0 + 1] - m1 * sc1;
        const _Float16* pbase0 =
            pooled + ((size_t)b * 225 + py0 * 15 + px0) * 32 + c0;
#pragma unroll
        for (int yi = 0; yi < 4; ++yi) {
            int yr = yh * 4 + yi;
            fp16v2 v2 = *(const fp16v2*)(pbase0 + yr * 480 + xx * 32);
            float va = fmaxf((float)v2.x * sc0 + sh0, 0.f);
            float vb = fmaxf((float)v2.y * sc1 + sh1, 0.f);
            float fa[5], fb5[5];
            expand5(va, fa);
            expand5(vb, fb5);
            int* eb = (int*)&Eu[(yr * 8 + xx) * EU_PS] + c2;
            eb[0]  = pkh(fa[0], fb5[0]);
            eb[16] = pkh(fa[1], fb5[1]);
            eb[32] = pkh(fa[2], fb5[2]);
            eb[48] = pkh(fa[3], fb5[3]);
            eb[64] = pkh(fa[4], fb5[4]);
        }
    }
    if (t < 80) ((int*)&Eu[64 * EU_PS])[t] = 0;  // zero position

    int abase[4][4];
#pragma unroll
    for (int mt = 0; mt < 4; ++mt) {
        int m = mt * 16 + l15;
        if (m < 49) {
            int pr = m / 7, pc = m - pr * 7;
#pragma unroll
            for (int s = 0; s < 4; ++s)
                abase[mt][s] = ((pr + (s >> 1)) * 8 + pc + (s & 1)) * EU_PS;
        } else {
#pragma unroll
            for (int s = 0; s < 4; ++s) abase[mt][s] = 64 * EU_PS;
        }
    }
    __syncthreads();

    f32x4 acc[4];
#pragma unroll
    for (int mt = 0; mt < 4; ++mt) acc[mt] = (f32x4){0.f, 0.f, 0.f, 0.f};

    c2_loadb(Wb, 1, bfB);
    c2_mfma(Eu, abase, 0, quad, bfA, acc);
    c2_loadb(Wb, 2, bfA);
    c2_mfma(Eu, abase, 1, quad, bfB, acc);
    c2_loadb(Wb, 3, bfB);
    c2_mfma(Eu, abase, 2, quad, bfA, acc);
    c2_mfma(Eu, abase, 3, quad, bfB, acc);

    // ---- store fp16 Pt ----
    int o = wv * 16 + l15;
#pragma unroll
    for (int mt = 0; mt < 4; ++mt) {
#pragma unroll
        for (int reg = 0; reg < 4; ++reg) {
            int m = mt * 16 + quad * 4 + reg;
            if (m < 49) {
                int pr = m / 7, pc = m - pr * 7;
                int patch = (b * 14 + py0 + pr) * 14 + px0 + pc;
                Pt[(size_t)patch * 64 + o] = (_Float16)acc[mt][reg];
            }
        }
    }
    float s = 0.f, s2 = 0.f;
#pragma unroll
    for (int mt = 0; mt < 4; ++mt)
#pragma unroll
        for (int reg = 0; reg < 4; ++reg) {
            float a = acc[mt][reg];
            s += a;
            s2 += a * a;
        }
    s  += __shfl_down(s, 16, 64);  s  += __shfl_down(s, 32, 64);
    s2 += __shfl_down(s2, 16, 64); s2 += __shfl_down(s2, 32, 64);
    if (lane < 16) {
        part[(size_t)blk * 128 + 2 * o]     = s;
        part[(size_t)blk * 128 + 2 * o + 1] = s2;
    }
}

// ---------- reduce slot-major partials (conv2 only) ----------

__global__ __launch_bounds__(256) void redstats_kernel(
        const float* __restrict__ part, float* __restrict__ stats,
        int nblk, int stride) {
    int p = blockIdx.x;
    float s = 0.f;
    for (int j = threadIdx.x; j < nblk; j += 256)
        s += part[(size_t)j * stride + p];
#pragma unroll
    for (int off = 32; off > 0; off >>= 1) s += __shfl_down(s, off, 64);
    __shared__ float ls[4];
    if ((threadIdx.x & 63) == 0) ls[threadIdx.x >> 6] = s;
    __syncthreads();
    if (threadIdx.x == 0) stats[p] = ls[0] + ls[1] + ls[2] + ls[3];
}

// ---------- fc1 (fused BN+ReLU+pool from Pt): 2 images/block, fdot2 ----------
// bnpool2 folded in: per block compute sc/sh once, read Pt directly, build
// the LDS x-buffer (pooled2 never materialized; saves 12.8 MB traffic,
// one kernel, one boundary). relu(max) == max(relu).

__global__ __launch_bounds__(256) void fc1_kernel(
        const _Float16* __restrict__ Pt, const float* __restrict__ stats,
        const float* __restrict__ g, const float* __restrict__ bb,
        const unsigned int* __restrict__ wTh2, const float* __restrict__ bias,
        float* __restrict__ z) {
    __shared__ unsigned int xsu[2 * 1568];
    __shared__ float red[2][4][64];
    __shared__ float scs[64], shs[64];
    int t = threadIdx.x;
    int b0 = blockIdx.x * 2;
    if (t < 64) {
        float mean = stats[2 * t] * (1.0f / 200704.0f);
        float var  = stats[2 * t + 1] * (1.0f / 200704.0f) - mean * mean;
        float sc = rsqrtf(var + BN_EPS) * g[t];
        scs[t] = sc;
        shs[t] = bb[t] - mean * sc;
    }
    __syncthreads();
    // fill xsu: 3136 c-pair tasks (img, q2, c2)
    for (int task = t; task < 3136; task += 256) {
        int img = task / 1568;
        int r = task - img * 1568;
        int q2 = r >> 5, c2 = r & 31;
        int c0 = c2 * 2;
        int py2 = q2 / 7, px2 = q2 - py2 * 7;
        int q = (py2 * 2) * 14 + px2 * 2;
        const _Float16* p = Pt + ((size_t)(b0 + img) * 196 + q) * 64 + c0;
        fp16v2 r0 = *(const fp16v2*)(p);
        fp16v2 r1 = *(const fp16v2*)(p + 64);
        fp16v2 r2 = *(const fp16v2*)(p + 14 * 64);
        fp16v2 r3 = *(const fp16v2*)(p + 15 * 64);
        float sc0 = scs[c0], sh0 = shs[c0];
        float sc1 = scs[c0 + 1], sh1 = shs[c0 + 1];
        float v0 = fmaxf(fmaxf((float)r0.x, (float)r1.x),
                         fmaxf((float)r2.x, (float)r3.x)) * sc0 + sh0;
        float v1 = fmaxf(fmaxf((float)r0.y, (float)r1.y),
                         fmaxf((float)r2.y, (float)r3.y)) * sc1 + sh1;
        // sc can be negative: max must be applied post-affine. Do it safely:
        float w0 = fmaxf(fmaxf((float)r0.x * sc0 + sh0, (float)r1.x * sc0 + sh0),
                         fmaxf((float)r2.x * sc0 + sh0, (float)r3.x * sc0 + sh0));
        float w1 = fmaxf(fmaxf((float)r0.y * sc1 + sh1, (float)r1.y * sc1 + sh1),
                         fmaxf((float)r2.y * sc1 + sh1, (float)r3.y * sc1 + sh1));
        (void)v0; (void)v1;
        xsu[task] = (unsigned int)pkh(fmaxf(w0, 0.f), fmaxf(w1, 0.f));
    }
    __syncthreads();
    int o = t & 63, qq = t >> 6;
    float s0 = 0.f, s1 = 0.f;
    const unsigned int* wp = wTh2 + (size_t)qq * 392 * 64 + o;
    int jb = qq * 392;
    for (int i = 0; i < 392; ++i) {
        union { unsigned int u; fp16v2 h; } uw, u0, u1;
        uw.u = wp[i * 64];
        u0.u = xsu[jb + i];
        u1.u = xsu[1568 + jb + i];
        s0 = __builtin_amdgcn_fdot2(u0.h, uw.h, s0, false);
        s1 = __builtin_amdgcn_fdot2(u1.h, uw.h, s1, false);
    }
    red[0][qq][o] = s0; red[1][qq][o] = s1;
    __syncthreads();
    if (t < 128) {
        int bb2 = t >> 6;
        int oo = t & 63;
        float tot = red[bb2][0][oo] + red[bb2][1][oo] + red[bb2][2][oo]
                  + red[bb2][3][oo] + bias[oo];
        z[((size_t)(b0 + bb2)) * 64 + oo] = tot;
    }
}

// ---------- bn1d column stats -> precomputed sc/sh ----------

__global__ __launch_bounds__(256) void colstats_kernel(
        const float* __restrict__ z, const float* __restrict__ g,
        const float* __restrict__ bb, float* __restrict__ scsh) {
    int c = blockIdx.x;
    float s = 0.f, s2 = 0.f;
    for (int b = threadIdx.x; b < 1024; b += 256) {
        float v = z[(size_t)b * 64 + c];
        s += v; s2 += v * v;
    }
#pragma unroll
    for (int off = 32; off > 0; off >>= 1) {
        s  += __shfl_down(s, off, 64);
        s2 += __shfl_down(s2, off, 64);
    }
    __shared__ float ls[8];
    int w = threadIdx.x >> 6;
    if ((threadIdx.x & 63) == 0) { ls[w * 2] = s; ls[w * 2 + 1] = s2; }
    __syncthreads();
    if (threadIdx.x == 0) {
        float st = ls[0] + ls[2] + ls[4] + ls[6];
        float st2 = ls[1] + ls[3] + ls[5] + ls[7];
        float mean = st * (1.0f / 1024.0f);
        float var  = st2 * (1.0f / 1024.0f) - mean * mean;
        float sc = rsqrtf(var + BN_EPS) * g[c];
        scsh[2 * c]     = sc;
        scsh[2 * c + 1] = bb[c] - mean * sc;
    }
}

// ---------- final: bn1d + relu + fc2 -> out [1024,10] ----------

__global__ __launch_bounds__(256) void final_kernel(
        const float* __restrict__ z, const float* __restrict__ scsh,
        const float* __restrict__ w2, const float* __restrict__ b2,
        float* __restrict__ out) {
    int t = blockIdx.x * 256 + threadIdx.x;
    if (t >= 10240) return;
    int o = t % 10, b = t / 10;
    float acc = b2[o];
#pragma unroll 8
    for (int c = 0; c < 64; ++c) {
        float a = fmaxf(z[(size_t)b * 64 + c] * scsh[2 * c] + scsh[2 * c + 1], 0.f);
        acc += a * w2[o * 64 + c];
    }
    out[t] = acc;
}

// ---------- launch ----------

extern "C" void kernel_launch(void* const* d_in, const int* in_sizes, int n_in,
                              void* d_out, int out_size, void* d_ws, size_t ws_size,
                              hipStream_t stream) {
    const float* x   = (const float*)d_in[0];
    const float* bw1 = (const float*)d_in[1];
    const float* sw1 = (const float*)d_in[2];
    const float* g1  = (const float*)d_in[3];
    const float* b1  = (const float*)d_in[4];
    const float* bw2 = (const float*)d_in[5];
    const float* sw2 = (const float*)d_in[6];
    const float* g2  = (const float*)d_in[7];
    const float* b2v = (const float*)d_in[8];
    const float* fw1 = (const float*)d_in[9];
    const float* fb1 = (const float*)d_in[10];
    const float* g3  = (const float*)d_in[11];
    const float* b3  = (const float*)d_in[12];
    const float* fw2 = (const float*)d_in[13];
    const float* fb2 = (const float*)d_in[14];
    float* out = (float*)d_out;

    char* ws = (char*)d_ws;
    _Float16* Pt     = (_Float16*)(ws);
    float* part2     = (float*)(ws + 51380224);
    _Float16* Wf     = (_Float16*)(ws + 100000000);
    _Float16* Wf1    = (_Float16*)(ws + 100131072);
    _Float16* pooled = (_Float16*)(ws + 125960192);
    float* z         = (float*)(ws + 155451392);
    unsigned int* wTh2 = (unsigned int*)(ws + 155713536);
    float* stats1    = (float*)(ws + 156516352);
    float* stats2    = (float*)(ws + 156516608);
    float* stats3    = (float*)(ws + 156517120);

    prep_kernel<<<560, 256, 0, stream>>>(fw1, wTh2, bw2, sw2, Wf, bw1, sw1, Wf1,
                                         stats1);

    conv1_kernel<<<1024, 256, 0, stream>>>(x, Wf1, pooled, stats1);

    conv2_kernel<<<4096, 256, 0, stream>>>(pooled, stats1, g1, b1,
                                           Wf, Pt, part2);
    redstats_kernel<<<128, 256, 0, stream>>>(part2, stats2, 4096, 128);

    fc1_kernel<<<512, 256, 0, stream>>>(Pt, stats2, g2, b2v, wTh2, fb1, z);
    colstats_kernel<<<64, 256, 0, stream>>>(z, g3, b3, stats3);
    final_kernel<<<(10240 + 255) / 256, 256, 0, stream>>>(z, stats3, fw2, fb2, out);
}

// Round 17
// 189.921 us; speedup vs baseline: 1.1820x; 1.0628x over previous
//
#include <hip/hip_runtime.h>
#include <math.h>

#define BN_EPS 1e-5f

typedef __attribute__((ext_vector_type(8))) _Float16 f16x8;
typedef __attribute__((ext_vector_type(4))) _Float16 f16x4;
typedef __attribute__((ext_vector_type(2))) __fp16 fp16v2;
typedef __attribute__((ext_vector_type(4))) float f32x4;

// ---------- helpers ----------

__device__ __forceinline__ float siluf(float v) {
    return v * __builtin_amdgcn_rcpf(1.0f + __expf(-v));
}

// 6*basis_i(x), i=0..3, cubic B-spline on knots g[j]=2j-7.
// 6*B(t) = max(0,2-|t|)^3 - 4*max(0,1-|t|)^3 with t = u-(i+2), u=(x+7)/2.
// The 1/6 is folded into the spline weights at prep time.
__device__ __forceinline__ void expand5(float v, float f[5]) {
    f[0] = siluf(v);
    float u = (v + 7.0f) * 0.5f;
#pragma unroll
    for (int i = 0; i < 4; ++i) {
        float a = fabsf(u - (float)(i + 2));
        float p = fmaxf(2.0f - a, 0.0f);
        float q = fmaxf(1.0f - a, 0.0f);
        f[i + 1] = p * p * p - 4.0f * (q * q * q);
    }
}

__device__ __forceinline__ int pkh(float a, float b) {
    union { fp16v2 h2; int i; } u;
    u.h2 = __builtin_amdgcn_cvt_pkrtz(a, b);
    return u.i;
}

// ---------- merged prep: fc1-w pack + conv2 weights + conv1 weights ----------

__global__ __launch_bounds__(256) void prep_kernel(
        const float* __restrict__ fw1, unsigned int* __restrict__ wTh2,
        const float* __restrict__ bw2, const float* __restrict__ sw2,
        _Float16* __restrict__ Wf,
        const float* __restrict__ bw1, const float* __restrict__ sw1,
        _Float16* __restrict__ Wf1) {
    int blk = blockIdx.x;
    if (blk < 392) {
        int t = blk * 256 + threadIdx.x;
        int o = t & 63;
        int j2 = t >> 6;
        int jc = (j2 * 2) & 63;
        int q2 = (j2 * 2) >> 6;
        wTh2[t] = (unsigned int)pkh(fw1[(size_t)o * 3136 + jc * 49 + q2],
                                    fw1[(size_t)o * 3136 + (jc + 1) * 49 + q2]);
    } else if (blk < 552) {
        int t = (blk - 392) * 256 + threadIdx.x;
        if (t >= 64 * 640) return;
        int n = t / 640;
        int k = t - n * 640;
        int s = k / 160;
        int r = k - s * 160;
        int f = r >> 5;
        int c = r & 31;
        float val = (f == 0) ? bw2[n * 128 + c * 4 + s]
                             : sw2[n * 512 + c * 16 + s * 4 + (f - 1)] * (1.0f / 6.0f);
        Wf[t] = (_Float16)val;
    } else {
        int t = (blk - 552) * 256 + threadIdx.x;
        if (t >= 32 * 64) return;
        int n = t >> 6;
        int k = t & 63;
        int s = k >> 4, j = k & 15;
        float val = 0.f;
        if (j < 15) {
            int f = j / 3, c = j - f * 3;
            int i = c * 4 + s;
            val = (f == 0) ? bw1[n * 12 + i]
                           : sw1[(n * 12 + i) * 4 + f - 1] * (1.0f / 6.0f);
        }
        Wf1[t] = (_Float16)val;
    }
}

// ---------- conv1: per-IMAGE block, unique-pixel expand + MFMA + pool + stats ----

__global__ __launch_bounds__(256, 4) void conv1_kernel(
        const float* __restrict__ x, const _Float16* __restrict__ Wf1,
        _Float16* __restrict__ pooled, float* __restrict__ part) {
    __shared__ _Float16 Eu[1025 * 16];
    __shared__ float Rs[4][64];
    char* EuB = (char*)Eu;

    int t = threadIdx.x;
    int lane = t & 63, wv = t >> 6;
    int quad = lane >> 4, l15 = lane & 15;
    int b = blockIdx.x;

    const _Float16* wb0 = Wf1 + (size_t)l15 * 64 + quad * 8;
    f16x8 bf00 = *(const f16x8*)(wb0);
    f16x8 bf01 = *(const f16x8*)(wb0 + 32);
    f16x8 bf10 = *(const f16x8*)(wb0 + 16 * 64);
    f16x8 bf11 = *(const f16x8*)(wb0 + 16 * 64 + 32);

    float xv[12];
    const float* xb = x + (size_t)b * 3072;
#pragma unroll
    for (int k = 0; k < 12; ++k) xv[k] = xb[t + k * 256];
#pragma unroll
    for (int k = 0; k < 12; ++k) {
        int idx = t + k * 256;
        int c = idx >> 10;
        int pos = idx & 1023;
        float f[5];
        expand5(xv[k], f);
        int rb = pos * 32;
        int key = (pos & 12) << 2;
        *(_Float16*)(EuB + ((rb + c * 2) ^ key))        = (_Float16)f[0];
        *(_Float16*)(EuB + ((rb + (3 + c) * 2) ^ key))  = (_Float16)f[1];
        *(_Float16*)(EuB + ((rb + (6 + c) * 2) ^ key))  = (_Float16)f[2];
        *(_Float16*)(EuB + ((rb + (9 + c) * 2) ^ key))  = (_Float16)f[3];
        *(_Float16*)(EuB + ((rb + (12 + c) * 2) ^ key)) = (_Float16)f[4];
    }
    if (t < 8) *(int*)(EuB + 32768 + t * 4) = 0;
    __syncthreads();

    int dxq = quad >> 1, hb = (quad & 1) * 16;
    int wxv = 8 * wv + (l15 & 7);
    int colb = wxv + dxq;
    int pbase = (colb * 32 + hb) ^ ((colb & 12) << 2);
    bool vx = wxv < 31;
    int pzero = 32768 + hb;
    int wy0 = l15 >> 3;

    float ss0 = 0.f, sq0 = 0.f, ss1 = 0.f, sq1 = 0.f;

    int p0 = vx ? wy0 * 1024 + pbase : pzero;
    f16x8 a0 = *(const f16x8*)(EuB + p0);
    f16x8 a1 = *(const f16x8*)(EuB + p0 + (vx ? 1024 : 0));

#pragma unroll 1
    for (int i = 0; i < 16; ++i) {
        f32x4 acc0 = (f32x4){0.f, 0.f, 0.f, 0.f};
        f32x4 acc1 = (f32x4){0.f, 0.f, 0.f, 0.f};
        acc0 = __builtin_amdgcn_mfma_f32_16x16x32_f16(a0, bf00, acc0, 0, 0, 0);
        acc1 = __builtin_amdgcn_mfma_f32_16x16x32_f16(a0, bf10, acc1, 0, 0, 0);
        acc0 = __builtin_amdgcn_mfma_f32_16x16x32_f16(a1, bf01, acc0, 0, 0, 0);
        acc1 = __builtin_amdgcn_mfma_f32_16x16x32_f16(a1, bf11, acc1, 0, 0, 0);
        if (i < 15) {
            int wyn = 2 * (i + 1) + wy0;
            bool vn = vx && (wyn < 31);
            int pn = vn ? wyn * 1024 + pbase : pzero;
            a0 = *(const f16x8*)(EuB + pn);
            a1 = *(const f16x8*)(EuB + pn + (vn ? 1024 : 0));
        }
        float h00 = fmaxf(acc0[0], acc0[1]);
        float h01 = fmaxf(acc0[2], acc0[3]);
        float h10 = fmaxf(acc1[0], acc1[1]);
        float h11 = fmaxf(acc1[2], acc1[3]);
        float g00 = fmaxf(h00, __shfl_down(h00, 32, 64));
        float g01 = fmaxf(h01, __shfl_down(h01, 32, 64));
        float g10 = fmaxf(h10, __shfl_down(h10, 32, 64));
        float g11 = fmaxf(h11, __shfl_down(h11, 32, 64));
        if (lane < 32 && i < 15) {
            int pn0 = 4 * wv + (quad & 1) * 2;
            size_t base = ((size_t)b * 225 + i * 15) * 32;
            if (pn0 < 15) {
                pooled[base + pn0 * 32 + l15]      = (_Float16)g00;
                pooled[base + pn0 * 32 + 16 + l15] = (_Float16)g10;
            }
            if (pn0 < 14) {
                pooled[base + (pn0 + 1) * 32 + l15]      = (_Float16)g01;
                pooled[base + (pn0 + 1) * 32 + 16 + l15] = (_Float16)g11;
            }
        }
        ss0 += acc0[0] + acc0[1] + acc0[2] + acc0[3];
        sq0 += acc0[0] * acc0[0] + acc0[1] * acc0[1]
             + acc0[2] * acc0[2] + acc0[3] * acc0[3];
        ss1 += acc1[0] + acc1[1] + acc1[2] + acc1[3];
        sq1 += acc1[0] * acc1[0] + acc1[1] * acc1[1]
             + acc1[2] * acc1[2] + acc1[3] * acc1[3];
    }

    ss0 += __shfl_down(ss0, 32, 64); ss0 += __shfl_down(ss0, 16, 64);
    sq0 += __shfl_down(sq0, 32, 64); sq0 += __shfl_down(sq0, 16, 64);
    ss1 += __shfl_down(ss1, 32, 64); ss1 += __shfl_down(ss1, 16, 64);
    sq1 += __shfl_down(sq1, 32, 64); sq1 += __shfl_down(sq1, 16, 64);
    if (lane < 16) {
        Rs[wv][2 * l15]          = ss0;
        Rs[wv][2 * l15 + 1]      = sq0;
        Rs[wv][32 + 2 * l15]     = ss1;
        Rs[wv][32 + 2 * l15 + 1] = sq1;
    }
    __syncthreads();
    if (t < 64)
        part[(size_t)b * 64 + t] = Rs[0][t] + Rs[1][t] + Rs[2][t] + Rs[3][t];
}

// ---------- conv2: N-split, unpadded Eu, B double-buffered (measured 52.7 us) ----

#define EU_PS 160  // halves per position, unpadded

__device__ __forceinline__ void c2_loadb(const _Float16* __restrict__ Wb,
                                         int g, f16x8 bf[5]) {
#pragma unroll
    for (int ks = 0; ks < 5; ++ks)
        bf[ks] = *(const f16x8*)(Wb + g * 160 + ks * 32);
}

__device__ __forceinline__ void c2_mfma(const _Float16* Eu,
                                        const int abase[4][4], int g,
                                        int quad, const f16x8 bf[5],
                                        f32x4 acc[4]) {
#pragma unroll
    for (int ks = 0; ks < 5; ++ks) {
        int jo = ks * 32 + quad * 8;
#pragma unroll
        for (int mt = 0; mt < 4; ++mt) {
            f16x8 a = *(const f16x8*)&Eu[abase[mt][g] + jo];
            acc[mt] = __builtin_amdgcn_mfma_f32_16x16x32_f16(a, bf[ks], acc[mt], 0, 0, 0);
        }
    }
}

__global__ __launch_bounds__(256, 7) void conv2_kernel(
        const _Float16* __restrict__ pooled, const float* __restrict__ stats1,
        const float* __restrict__ g1v, const float* __restrict__ b1v,
        const _Float16* __restrict__ Wf, _Float16* __restrict__ Pt,
        float* __restrict__ part) {
    __shared__ _Float16 Eu[65 * EU_PS];

    int t = threadIdx.x;
    int lane = t & 63, wv = t >> 6;
    int quad = lane >> 4, l15 = lane & 15;

    int blk = blockIdx.x;
    int b = blk >> 2;
    int py0 = ((blk >> 1) & 1) * 7;
    int px0 = (blk & 1) * 7;

    const _Float16* Wb = Wf + (size_t)(wv * 16 + l15) * 640 + quad * 8;
    f16x8 bfA[5], bfB[5];
    c2_loadb(Wb, 0, bfA);

    // ---- phase 1: 8x8 pixels x 32 ch; thread = (c-pair, xx, y-half) ----
    {
        int c2 = t & 15, c0 = c2 * 2;
        int xx = (t >> 4) & 7;
        int yh = t >> 7;
        const float invN1 = 1.0f / (1024.0f * 961.0f);
        float m0 = stats1[2 * c0] * invN1;
        float v0 = stats1[2 * c0 + 1] * invN1 - m0 * m0;
        float sc0 = rsqrtf(v0 + BN_EPS) * g1v[c0];
        float sh0 = b1v[c0] - m0 * sc0;
        float m1 = stats1[2 * c0 + 2] * invN1;
        float v1 = stats1[2 * c0 + 3] * invN1 - m1 * m1;
        float sc1 = rsqrtf(v1 + BN_EPS) * g1v[c0 + 1];
        float sh1 = b1v[c0 + 1] - m1 * sc1;
        const _Float16* pbase0 =
            pooled + ((size_t)b * 225 + py0 * 15 + px0) * 32 + c0;
#pragma unroll
        for (int yi = 0; yi < 4; ++yi) {
            int yr = yh * 4 + yi;
            fp16v2 v2 = *(const fp16v2*)(pbase0 + yr * 480 + xx * 32);
            float va = fmaxf((float)v2.x * sc0 + sh0, 0.f);
            float vb = fmaxf((float)v2.y * sc1 + sh1, 0.f);
            float fa[5], fb5[5];
            expand5(va, fa);
            expand5(vb, fb5);
            int* eb = (int*)&Eu[(yr * 8 + xx) * EU_PS] + c2;
            eb[0]  = pkh(fa[0], fb5[0]);
            eb[16] = pkh(fa[1], fb5[1]);
            eb[32] = pkh(fa[2], fb5[2]);
            eb[48] = pkh(fa[3], fb5[3]);
            eb[64] = pkh(fa[4], fb5[4]);
        }
    }
    if (t < 80) ((int*)&Eu[64 * EU_PS])[t] = 0;  // zero position

    int abase[4][4];
#pragma unroll
    for (int mt = 0; mt < 4; ++mt) {
        int m = mt * 16 + l15;
        if (m < 49) {
            int pr = m / 7, pc = m - pr * 7;
#pragma unroll
            for (int s = 0; s < 4; ++s)
                abase[mt][s] = ((pr + (s >> 1)) * 8 + pc + (s & 1)) * EU_PS;
        } else {
#pragma unroll
            for (int s = 0; s < 4; ++s) abase[mt][s] = 64 * EU_PS;
        }
    }
    __syncthreads();

    f32x4 acc[4];
#pragma unroll
    for (int mt = 0; mt < 4; ++mt) acc[mt] = (f32x4){0.f, 0.f, 0.f, 0.f};

    c2_loadb(Wb, 1, bfB);
    c2_mfma(Eu, abase, 0, quad, bfA, acc);
    c2_loadb(Wb, 2, bfA);
    c2_mfma(Eu, abase, 1, quad, bfB, acc);
    c2_loadb(Wb, 3, bfB);
    c2_mfma(Eu, abase, 2, quad, bfA, acc);
    c2_mfma(Eu, abase, 3, quad, bfB, acc);

    // ---- store fp16 Pt ----
    int o = wv * 16 + l15;
#pragma unroll
    for (int mt = 0; mt < 4; ++mt) {
#pragma unroll
        for (int reg = 0; reg < 4; ++reg) {
            int m = mt * 16 + quad * 4 + reg;
            if (m < 49) {
                int pr = m / 7, pc = m - pr * 7;
                int patch = (b * 14 + py0 + pr) * 14 + px0 + pc;
                Pt[(size_t)patch * 64 + o] = (_Float16)acc[mt][reg];
            }
        }
    }
    float s = 0.f, s2 = 0.f;
#pragma unroll
    for (int mt = 0; mt < 4; ++mt)
#pragma unroll
        for (int reg = 0; reg < 4; ++reg) {
            float a = acc[mt][reg];
            s += a;
            s2 += a * a;
        }
    s  += __shfl_down(s, 16, 64);  s  += __shfl_down(s, 32, 64);
    s2 += __shfl_down(s2, 16, 64); s2 += __shfl_down(s2, 32, 64);
    if (lane < 16) {
        part[(size_t)blk * 128 + 2 * o]     = s;
        part[(size_t)blk * 128 + 2 * o + 1] = s2;
    }
}

// ---------- reduce slot-major partials ----------

__global__ __launch_bounds__(256) void redstats_kernel(
        const float* __restrict__ part, float* __restrict__ stats,
        int nblk, int stride) {
    int p = blockIdx.x;
    float s = 0.f;
    for (int j = threadIdx.x; j < nblk; j += 256)
        s += part[(size_t)j * stride + p];
#pragma unroll
    for (int off = 32; off > 0; off >>= 1) s += __shfl_down(s, off, 64);
    __shared__ float ls[4];
    if ((threadIdx.x & 63) == 0) ls[threadIdx.x >> 6] = s;
    __syncthreads();
    if (threadIdx.x == 0) stats[p] = ls[0] + ls[1] + ls[2] + ls[3];
}

// ---------- BN + ReLU + pool, fp16 in/out, 4 ch per thread ----------

__global__ __launch_bounds__(256) void bnpool2_kernel(
        const _Float16* __restrict__ Pt, const float* __restrict__ stats,
        const float* __restrict__ g, const float* __restrict__ bb,
        _Float16* __restrict__ out) {
    int t = blockIdx.x * 256 + threadIdx.x;
    if (t >= 1024 * 49 * 16) return;
    int c4 = (t & 15) * 4;
    int q2 = (t >> 4) % 49;
    int b  = t / (49 * 16);
    float sc[4], sh[4];
#pragma unroll
    for (int j = 0; j < 4; ++j) {
        int c = c4 + j;
        float mean = stats[2 * c] * (1.0f / 200704.0f);
        float var  = stats[2 * c + 1] * (1.0f / 200704.0f) - mean * mean;
        sc[j] = rsqrtf(var + BN_EPS) * g[c];
        sh[j] = bb[c] - mean * sc[j];
    }
    int py2 = q2 / 7, px2 = q2 - py2 * 7;
    int q = (py2 * 2) * 14 + px2 * 2;
    const _Float16* p = Pt + ((size_t)b * 196 + q) * 64 + c4;
    f16x4 r0 = *(const f16x4*)(p);
    f16x4 r1 = *(const f16x4*)(p + 64);
    f16x4 r2 = *(const f16x4*)(p + 14 * 64);
    f16x4 r3 = *(const f16x4*)(p + 15 * 64);
    f16x4 res;
#pragma unroll
    for (int j = 0; j < 4; ++j) {
        float v0 = fmaxf((float)r0[j] * sc[j] + sh[j], 0.f);
        float v1 = fmaxf((float)r1[j] * sc[j] + sh[j], 0.f);
        float v2 = fmaxf((float)r2[j] * sc[j] + sh[j], 0.f);
        float v3 = fmaxf((float)r3[j] * sc[j] + sh[j], 0.f);
        res[j] = (_Float16)fmaxf(fmaxf(v0, v1), fmaxf(v2, v3));
    }
    *(f16x4*)(out + (size_t)b * 3136 + q2 * 64 + c4) = res;
}

// ---------- fc1: 2 images/block, fdot2 ----------

__global__ __launch_bounds__(256) void fc1_kernel(
        const _Float16* __restrict__ xin, const unsigned int* __restrict__ wTh2,
        const float* __restrict__ bias, float* __restrict__ z) {
    __shared__ unsigned int xsu[2 * 1568];
    __shared__ float red[2][4][64];
    int b0 = blockIdx.x * 2;
    const unsigned int* xg = (const unsigned int*)xin + (size_t)b0 * 1568;
    for (int j = threadIdx.x; j < 2 * 1568; j += 256) xsu[j] = xg[j];
    __syncthreads();
    int o = threadIdx.x & 63, q = threadIdx.x >> 6;
    float s0 = 0.f, s1 = 0.f;
    const unsigned int* wp = wTh2 + (size_t)q * 392 * 64 + o;
    int jb = q * 392;
    for (int i = 0; i < 392; ++i) {
        union { unsigned int u; fp16v2 h; } uw, u0, u1;
        uw.u = wp[i * 64];
        u0.u = xsu[jb + i];
        u1.u = xsu[1568 + jb + i];
        s0 = __builtin_amdgcn_fdot2(u0.h, uw.h, s0, false);
        s1 = __builtin_amdgcn_fdot2(u1.h, uw.h, s1, false);
    }
    red[0][q][o] = s0; red[1][q][o] = s1;
    __syncthreads();
    if (threadIdx.x < 128) {
        int bb = threadIdx.x >> 6;
        int oo = threadIdx.x & 63;
        float tot = red[bb][0][oo] + red[bb][1][oo] + red[bb][2][oo]
                  + red[bb][3][oo] + bias[oo];
        z[((size_t)(b0 + bb)) * 64 + oo] = tot;
    }
}

// ---------- bn1d column stats -> precomputed sc/sh ----------

__global__ __launch_bounds__(256) void colstats_kernel(
        const float* __restrict__ z, const float* __restrict__ g,
        const float* __restrict__ bb, float* __restrict__ scsh) {
    int c = blockIdx.x;
    float s = 0.f, s2 = 0.f;
    for (int b = threadIdx.x; b < 1024; b += 256) {
        float v = z[(size_t)b * 64 + c];
        s += v; s2 += v * v;
    }
#pragma unroll
    for (int off = 32; off > 0; off >>= 1) {
        s  += __shfl_down(s, off, 64);
        s2 += __shfl_down(s2, off, 64);
    }
    __shared__ float ls[8];
    int w = threadIdx.x >> 6;
    if ((threadIdx.x & 63) == 0) { ls[w * 2] = s; ls[w * 2 + 1] = s2; }
    __syncthreads();
    if (threadIdx.x == 0) {
        float st = ls[0] + ls[2] + ls[4] + ls[6];
        float st2 = ls[1] + ls[3] + ls[5] + ls[7];
        float mean = st * (1.0f / 1024.0f);
        float var  = st2 * (1.0f / 1024.0f) - mean * mean;
        float sc = rsqrtf(var + BN_EPS) * g[c];
        scsh[2 * c]     = sc;
        scsh[2 * c + 1] = bb[c] - mean * sc;
    }
}

// ---------- final: bn1d + relu + fc2 -> out [1024,10] ----------

__global__ __launch_bounds__(256) void final_kernel(
        const float* __restrict__ z, const float* __restrict__ scsh,
        const float* __restrict__ w2, const float* __restrict__ b2,
        float* __restrict__ out) {
    int t = blockIdx.x * 256 + threadIdx.x;
    if (t >= 10240) return;
    int o = t % 10, b = t / 10;
    float acc = b2[o];
#pragma unroll 8
    for (int c = 0; c < 64; ++c) {
        float a = fmaxf(z[(size_t)b * 64 + c] * scsh[2 * c] + scsh[2 * c + 1], 0.f);
        acc += a * w2[o * 64 + c];
    }
    out[t] = acc;
}

// ---------- launch ----------

extern "C" void kernel_launch(void* const* d_in, const int* in_sizes, int n_in,
                              void* d_out, int out_size, void* d_ws, size_t ws_size,
                              hipStream_t stream) {
    const float* x   = (const float*)d_in[0];
    const float* bw1 = (const float*)d_in[1];
    const float* sw1 = (const float*)d_in[2];
    const float* g1  = (const float*)d_in[3];
    const float* b1  = (const float*)d_in[4];
    const float* bw2 = (const float*)d_in[5];
    const float* sw2 = (const float*)d_in[6];
    const float* g2  = (const float*)d_in[7];
    const float* b2v = (const float*)d_in[8];
    const float* fw1 = (const float*)d_in[9];
    const float* fb1 = (const float*)d_in[10];
    const float* g3  = (const float*)d_in[11];
    const float* b3  = (const float*)d_in[12];
    const float* fw2 = (const float*)d_in[13];
    const float* fb2 = (const float*)d_in[14];
    float* out = (float*)d_out;

    char* ws = (char*)d_ws;
    float* part1     = (float*)(ws);
    _Float16* Pt     = (_Float16*)(ws);
    float* part2     = (float*)(ws + 51380224);
    _Float16* Wf     = (_Float16*)(ws + 100000000);
    _Float16* Wf1    = (_Float16*)(ws + 100131072);
    _Float16* pooled = (_Float16*)(ws + 125960192);
    float* z         = (float*)(ws + 155451392);
    unsigned int* wTh2 = (unsigned int*)(ws + 155713536);
    float* stats1    = (float*)(ws + 156516352);
    float* stats2    = (float*)(ws + 156516608);
    float* stats3    = (float*)(ws + 156517120);

    prep_kernel<<<560, 256, 0, stream>>>(fw1, wTh2, bw2, sw2, Wf, bw1, sw1, Wf1);

    conv1_kernel<<<1024, 256, 0, stream>>>(x, Wf1, pooled, part1);
    redstats_kernel<<<64, 256, 0, stream>>>(part1, stats1, 1024, 64);

    conv2_kernel<<<4096, 256, 0, stream>>>(pooled, stats1, g1, b1,
                                           Wf, Pt, part2);
    redstats_kernel<<<128, 256, 0, stream>>>(part2, stats2, 4096, 128);

    _Float16* pooled2 = pooled;
    bnpool2_kernel<<<(1024 * 49 * 16 + 255) / 256, 256, 0, stream>>>(
        Pt, stats2, g2, b2v, pooled2);

    fc1_kernel<<<512, 256, 0, stream>>>(pooled2, wTh2, fb1, z);
    colstats_kernel<<<64, 256, 0, stream>>>(z, g3, b3, stats3);
    final_kernel<<<(10240 + 255) / 256, 256, 0, stream>>>(z, stats3, fw2, fb2, out);
}